// Round 5
// baseline (1200.548 us; speedup 1.0000x reference)
//
#include <hip/hip_runtime.h>

#define N_MI 100000
#define N_DI 50000
#define MI_P 100352   // multiple of 256
#define DI_P 50176    // multiple of 256

typedef _Float16 half8  __attribute__((ext_vector_type(8)));
typedef _Float16 half4  __attribute__((ext_vector_type(4)));
typedef float    floatx4 __attribute__((ext_vector_type(4)));

// ---------------------------------------------------------------------------
// CSR build
// ---------------------------------------------------------------------------
__global__ void count_kernel(const int* __restrict__ src, const int* __restrict__ dst,
                             int* deg_mi, int* deg_di, int E) {
    int i = blockIdx.x * blockDim.x + threadIdx.x;
    if (i < E) {
        atomicAdd(&deg_mi[src[i]], 1);
        atomicAdd(&deg_di[dst[i]], 1);
    }
}

__global__ __launch_bounds__(1024) void scan_kernel(const int* __restrict__ deg_di,
                                                    const int* __restrict__ deg_mi,
                                                    int* row_di, int* row_mi) {
    const int* deg;
    int* row;
    int n;
    if (blockIdx.x == 0) { deg = deg_di; row = row_di; n = N_DI; }
    else                 { deg = deg_mi; row = row_mi; n = N_MI; }

    __shared__ int wsum[16];
    int t = threadIdx.x;
    int lane = t & 63;
    int w = t >> 6;
    int carry = 0;

    for (int base = 0; base < n; base += 1024) {
        int i = base + t;
        int v = (i < n) ? deg[i] : 0;
        int x = v;
        #pragma unroll
        for (int off = 1; off < 64; off <<= 1) {
            int y = __shfl_up(x, off, 64);
            if (lane >= off) x += y;
        }
        if (lane == 63) wsum[w] = x;
        __syncthreads();
        if (w == 0 && lane < 16) {
            int s = wsum[lane];
            #pragma unroll
            for (int off = 1; off < 16; off <<= 1) {
                int y = __shfl_up(s, off, 16);
                if (lane >= off) s += y;
            }
            wsum[lane] = s;
        }
        __syncthreads();
        int woff = (w == 0) ? 0 : wsum[w - 1];
        int incl = x + woff;
        if (i < n) row[i] = carry + incl - v;
        carry += wsum[15];
        __syncthreads();
    }
    if (t == 0) row[n] = carry;
}

__global__ void fill_kernel(const int* __restrict__ src, const int* __restrict__ dst,
                            const int* __restrict__ row_mi, const int* __restrict__ row_di,
                            int* cur_mi, int* cur_di, int* csr_mi, int* csr_di, int E) {
    int i = blockIdx.x * blockDim.x + threadIdx.x;
    if (i >= E) return;
    int s = src[i], d = dst[i];
    int p = atomicAdd(&cur_di[d], 1);
    csr_di[row_di[d] + p] = s;
    int q = atomicAdd(&cur_mi[s], 1);
    csr_mi[row_mi[s] + q] = d;
}

// ---------------------------------------------------------------------------
// fp32 -> fp16 converts
// ---------------------------------------------------------------------------
__global__ void cvt_kernel(const float* __restrict__ s, _Float16* __restrict__ d, int n4) {
    int i = blockIdx.x * blockDim.x + threadIdx.x;
    if (i < n4) {
        float4 v = ((const float4*)s)[i];
        half4 h = {(_Float16)v.x, (_Float16)v.y, (_Float16)v.z, (_Float16)v.w};
        ((half4*)d)[i] = h;
    }
}

struct Cvt14 {
    const float* s[14];
    _Float16* d[14];
    int n4[14];
};

__global__ void cvt14_kernel(Cvt14 a) {
    int arr = blockIdx.y;
    int i = blockIdx.x * blockDim.x + threadIdx.x;
    if (i < a.n4[arr]) {
        float4 v = ((const float4*)a.s[arr])[i];
        half4 h = {(_Float16)v.x, (_Float16)v.y, (_Float16)v.z, (_Float16)v.w};
        ((half4*)a.d[arr])[i] = h;
    }
}

// ---------------------------------------------------------------------------
// Mean aggregation: one node per wave. din=128 -> 4 neighbors/pass; din=256 ->
// 2 neighbors/pass. fp32 acc, shfl reduce.
// ---------------------------------------------------------------------------
template<int DIN>
__global__ __launch_bounds__(256) void agg2_kernel(const _Float16* __restrict__ hsrc,
                                                   const int* __restrict__ row,
                                                   const int* __restrict__ csr,
                                                   _Float16* __restrict__ out, int n) {
    constexpr int LPR = DIN / 8;    // lanes per row chunk: 16 or 32
    constexpr int GR  = 64 / LPR;   // neighbor groups per wave: 4 or 2
    int node = blockIdx.x * 4 + (threadIdx.x >> 6);
    if (node >= n) return;
    int lane = threadIdx.x & 63;
    int g = lane / LPR, c = lane % LPR;
    int beg = row[node], end = row[node + 1];
    float acc[8] = {};
    #pragma unroll 2
    for (int j = beg + g; j < end; j += GR) {
        half8 v = *(const half8*)(hsrc + (long)csr[j] * DIN + c * 8);
        #pragma unroll
        for (int e = 0; e < 8; ++e) acc[e] += (float)v[e];
    }
    float inv = 1.f / (float)max(end - beg, 1);
    half8 o;
    #pragma unroll
    for (int e = 0; e < 8; ++e) {
        float s = acc[e];
        s += __shfl_down(s, 32);
        if (GR == 4) s += __shfl_down(s, 16);
        o[e] = (_Float16)(s * inv);
    }
    if (g == 0) *(half8*)(out + (long)node * DIN + c * 8) = o;
}

// ---------------------------------------------------------------------------
// Max-TLP fp16 MFMA GEMM: ONE 16x64 tile per wave, no LDS, no barriers.
// acc = 16 VGPR; per k-iter: 1 A half8 load + 4 W half8 loads + 4 MFMA.
// Latency hidden by residency (6 waves/SIMD) x huge grids, not per-wave ILP.
// Waves of a block share the A-row panel (L1 reuse); A is read exactly once.
// grid.x = (Mpad/16) * NN / 4;  N = NN*64.
// ---------------------------------------------------------------------------
template<int KI, bool DUAL, int NN>
__global__ __launch_bounds__(256, 6) void hgemm_t(
    const _Float16* __restrict__ A1, const _Float16* __restrict__ W1,
    const _Float16* __restrict__ A2, const _Float16* __restrict__ W2,
    const float* __restrict__ bias, const float* __restrict__ Cadd,
    _Float16* __restrict__ C, int M, int N, int relu)
{
    constexpr int K = KI * 32;
    const int w = blockIdx.x * 4 + (threadIdx.x >> 6);
    const int lane = threadIdx.x & 63;
    const int quad = lane >> 4, lr = lane & 15;
    const int mt = w / NN, nt = w % NN;
    const int n0 = nt * 64;
    const long arow = (long)(mt * 16 + lr) * K + quad * 8;

    floatx4 acc[4] = {};

    {
        const _Float16* Ab = A1 + arow;
        #pragma unroll
        for (int k = 0; k < KI; ++k) {
            half8 a = *(const half8*)(Ab + k * 32);
            #pragma unroll
            for (int j = 0; j < 4; ++j) {
                half8 b = *(const half8*)(W1 + (long)(n0 + j * 16 + lr) * K + k * 32 + quad * 8);
                acc[j] = __builtin_amdgcn_mfma_f32_16x16x32_f16(a, b, acc[j], 0, 0, 0);
            }
        }
    }
    if (DUAL) {
        const _Float16* Ab = A2 + arow;
        #pragma unroll
        for (int k = 0; k < KI; ++k) {
            half8 a = *(const half8*)(Ab + k * 32);
            #pragma unroll
            for (int j = 0; j < 4; ++j) {
                half8 b = *(const half8*)(W2 + (long)(n0 + j * 16 + lr) * K + k * 32 + quad * 8);
                acc[j] = __builtin_amdgcn_mfma_f32_16x16x32_f16(a, b, acc[j], 0, 0, 0);
            }
        }
    }

    // epilogue: C/D layout col(lane&15)=n, row(quad*4+r)=m
    const int mrow = mt * 16 + quad * 4;
    #pragma unroll
    for (int j = 0; j < 4; ++j) {
        int n = n0 + j * 16 + lr;
        float bn = bias[n];
        #pragma unroll
        for (int r = 0; r < 4; ++r) {
            int m = mrow + r;
            if (m < M) {
                float v = acc[j][r] + bn;
                if (Cadd) v += Cadd[(long)m * N + n];
                if (relu) v = fmaxf(v, 0.f);
                C[(long)m * N + n] = (_Float16)v;
            }
        }
    }
}

// ---------------------------------------------------------------------------
// Classifier: out[e] = dot64(h_mi[ls[e]], h_di[ld[e]]), fp16 in, fp32 out
// ---------------------------------------------------------------------------
__global__ void classify_kernel(const _Float16* __restrict__ hmi, const _Float16* __restrict__ hdi,
                                const int* __restrict__ ls, const int* __restrict__ ld,
                                float* __restrict__ out, int L) {
    long idx = (long)blockIdx.x * blockDim.x + threadIdx.x;
    int e = (int)(idx >> 4), q = (int)(idx & 15);
    if (e >= L) return;
    const half4* ra = (const half4*)(hmi + (long)ls[e] * 64);
    const half4* rb = (const half4*)(hdi + (long)ld[e] * 64);
    half4 a = ra[q], b = rb[q];
    float s = (float)a.x * (float)b.x + (float)a.y * (float)b.y +
              (float)a.z * (float)b.z + (float)a.w * (float)b.w;
    #pragma unroll
    for (int off = 8; off >= 1; off >>= 1) s += __shfl_down(s, off, 16);
    if (q == 0) out[e] = s;
}

// ---------------------------------------------------------------------------
// Launch
// ---------------------------------------------------------------------------
extern "C" void kernel_launch(void* const* d_in, const int* in_sizes, int n_in,
                              void* d_out, int out_size, void* d_ws, size_t ws_size,
                              hipStream_t stream) {
    const float* x_mi   = (const float*)d_in[0];
    const float* x_di   = (const float*)d_in[1];
    const float* W_mi   = (const float*)d_in[2];
    const float* b_mi   = (const float*)d_in[3];
    const float* W_di   = (const float*)d_in[4];
    const float* b_di   = (const float*)d_in[5];
    const float* emb_mi = (const float*)d_in[6];
    const float* emb_di = (const float*)d_in[7];
    const float* Wl1_md = (const float*)d_in[8];
    const float* bl1_md = (const float*)d_in[9];
    const float* Wr1_md = (const float*)d_in[10];
    const float* Wl1_dm = (const float*)d_in[11];
    const float* bl1_dm = (const float*)d_in[12];
    const float* Wr1_dm = (const float*)d_in[13];
    const float* Wl2_md = (const float*)d_in[14];
    const float* bl2_md = (const float*)d_in[15];
    const float* Wr2_md = (const float*)d_in[16];
    const float* Wl2_dm = (const float*)d_in[17];
    const float* bl2_dm = (const float*)d_in[18];
    const float* Wr2_dm = (const float*)d_in[19];
    const float* Wl3_md = (const float*)d_in[20];
    const float* bl3_md = (const float*)d_in[21];
    const float* Wr3_md = (const float*)d_in[22];
    const float* Wl3_dm = (const float*)d_in[23];
    const float* bl3_dm = (const float*)d_in[24];
    const float* Wr3_dm = (const float*)d_in[25];
    const int* edge_src  = (const int*)d_in[26];
    const int* edge_dst  = (const int*)d_in[27];
    const int* label_src = (const int*)d_in[28];
    const int* label_dst = (const int*)d_in[29];
    const int E = in_sizes[26];
    const int L = in_sizes[28];
    float* out = (float*)d_out;

    // ---- workspace layout (fp16 first, then ints) ----
    _Float16* hp = (_Float16*)d_ws;
    _Float16* xh_mi = hp; hp += (long)MI_P * 256;
    _Float16* xh_di = hp; hp += (long)DI_P * 128;
    _Float16* wWmi  = hp; hp += 128 * 256;
    _Float16* wWdi  = hp; hp += 128 * 128;
    _Float16* wl1md = hp; hp += 256 * 128;
    _Float16* wr1md = hp; hp += 256 * 128;
    _Float16* wl1dm = hp; hp += 256 * 128;
    _Float16* wr1dm = hp; hp += 256 * 128;
    _Float16* wl2md = hp; hp += 128 * 256;
    _Float16* wr2md = hp; hp += 128 * 256;
    _Float16* wl2dm = hp; hp += 128 * 256;
    _Float16* wr2dm = hp; hp += 128 * 256;
    _Float16* wl3md = hp; hp += 64 * 128;
    _Float16* wr3md = hp; hp += 64 * 128;
    _Float16* wl3dm = hp; hp += 64 * 128;
    _Float16* wr3dm = hp; hp += 64 * 128;
    _Float16* h_mi0 = hp; hp += (long)MI_P * 256;
    _Float16* h_mi1 = hp; hp += (long)MI_P * 256;
    _Float16* h_di0 = hp; hp += (long)DI_P * 256;
    _Float16* h_di1 = hp; hp += (long)DI_P * 256;
    _Float16* aggh  = hp; hp += (long)MI_P * 256;

    int* ip = (int*)hp;
    int* deg_di = ip;  ip += N_DI;
    int* deg_mi = ip;  ip += N_MI;
    int* cur_di = ip;  ip += N_DI;
    int* cur_mi = ip;  ip += N_MI;
    int* row_di = ip;  ip += N_DI + 1;
    int* row_mi = ip;  ip += N_MI + 1;
    int* csr_di = ip;  ip += E;
    int* csr_mi = ip;  ip += E;

    // ---- CSR build ----
    hipMemsetAsync(deg_di, 0, (size_t)(2 * (N_DI + N_MI)) * sizeof(int), stream);
    int eb = (E + 255) / 256;
    count_kernel<<<eb, 256, 0, stream>>>(edge_src, edge_dst, deg_mi, deg_di, E);
    scan_kernel<<<2, 1024, 0, stream>>>(deg_di, deg_mi, row_di, row_mi);
    fill_kernel<<<eb, 256, 0, stream>>>(edge_src, edge_dst, row_mi, row_di,
                                        cur_mi, cur_di, csr_mi, csr_di, E);

    // ---- converts ----
    cvt_kernel<<<(N_MI * 256 / 4 + 255) / 256, 256, 0, stream>>>(x_mi, xh_mi, N_MI * 256 / 4);
    cvt_kernel<<<(N_DI * 128 / 4 + 255) / 256, 256, 0, stream>>>(x_di, xh_di, N_DI * 128 / 4);
    Cvt14 cv;
    const float* srcs[14] = {W_mi, W_di, Wl1_md, Wr1_md, Wl1_dm, Wr1_dm,
                             Wl2_md, Wr2_md, Wl2_dm, Wr2_dm, Wl3_md, Wr3_md, Wl3_dm, Wr3_dm};
    _Float16* dsts[14] = {wWmi, wWdi, wl1md, wr1md, wl1dm, wr1dm,
                          wl2md, wr2md, wl2dm, wr2dm, wl3md, wr3md, wl3dm, wr3dm};
    int ns[14] = {32768, 16384, 32768, 32768, 32768, 32768,
                  32768, 32768, 32768, 32768, 8192, 8192, 8192, 8192};
    for (int i = 0; i < 14; ++i) { cv.s[i] = srcs[i]; cv.d[i] = dsts[i]; cv.n4[i] = ns[i] / 4; }
    cvt14_kernel<<<dim3(32, 14), 256, 0, stream>>>(cv);

    // ---- init: h0 = x @ W^T + b + emb ----
    hgemm_t<8, false, 2><<<MI_P / 16 * 2 / 4, 256, 0, stream>>>(
        xh_mi, wWmi, nullptr, nullptr, b_mi, emb_mi, h_mi0, N_MI, 128, 0);
    hgemm_t<4, false, 2><<<DI_P / 16 * 2 / 4, 256, 0, stream>>>(
        xh_di, wWdi, nullptr, nullptr, b_di, emb_di, h_di0, N_DI, 128, 0);

    // ---- Layer 1: 128 -> 256, relu ----
    agg2_kernel<128><<<(N_DI + 3) / 4, 256, 0, stream>>>(h_mi0, row_di, csr_di, aggh, N_DI);
    hgemm_t<4, true, 4><<<DI_P / 16 * 4 / 4, 256, 0, stream>>>(
        aggh, wl1md, h_di0, wr1md, bl1_md, nullptr, h_di1, N_DI, 256, 1);
    agg2_kernel<128><<<(N_MI + 3) / 4, 256, 0, stream>>>(h_di0, row_mi, csr_mi, aggh, N_MI);
    hgemm_t<4, true, 4><<<MI_P / 16 * 4 / 4, 256, 0, stream>>>(
        aggh, wl1dm, h_mi0, wr1dm, bl1_dm, nullptr, h_mi1, N_MI, 256, 1);

    // ---- Layer 2: 256 -> 128, relu ----
    agg2_kernel<256><<<(N_DI + 3) / 4, 256, 0, stream>>>(h_mi1, row_di, csr_di, aggh, N_DI);
    hgemm_t<8, true, 2><<<DI_P / 16 * 2 / 4, 256, 0, stream>>>(
        aggh, wl2md, h_di1, wr2md, bl2_md, nullptr, h_di0, N_DI, 128, 1);
    agg2_kernel<256><<<(N_MI + 3) / 4, 256, 0, stream>>>(h_di1, row_mi, csr_mi, aggh, N_MI);
    hgemm_t<8, true, 2><<<MI_P / 16 * 2 / 4, 256, 0, stream>>>(
        aggh, wl2dm, h_mi1, wr2dm, bl2_dm, nullptr, h_mi0, N_MI, 128, 1);

    // ---- Layer 3: 128 -> 64, no relu ----
    agg2_kernel<128><<<(N_DI + 3) / 4, 256, 0, stream>>>(h_mi0, row_di, csr_di, aggh, N_DI);
    hgemm_t<4, true, 1><<<DI_P / 16 * 1 / 4, 256, 0, stream>>>(
        aggh, wl3md, h_di0, wr3md, bl3_md, nullptr, h_di1, N_DI, 64, 0);
    agg2_kernel<128><<<(N_MI + 3) / 4, 256, 0, stream>>>(h_di0, row_mi, csr_mi, aggh, N_MI);
    hgemm_t<4, true, 1><<<MI_P / 16 * 1 / 4, 256, 0, stream>>>(
        aggh, wl3dm, h_mi0, wr3dm, bl3_dm, nullptr, h_mi1, N_MI, 64, 0);

    // ---- classifier ----
    classify_kernel<<<((long)L * 16 + 255) / 256, 256, 0, stream>>>(
        h_mi1, h_di1, label_src, label_dst, out, L);
}

// Round 6
// 972.386 us; speedup vs baseline: 1.2346x; 1.2346x over previous
//
#include <hip/hip_runtime.h>

#define N_MI 100000
#define N_DI 50000
#define MI_P 100352   // multiple of 256
#define DI_P 50176    // multiple of 256

typedef _Float16 half8  __attribute__((ext_vector_type(8)));
typedef _Float16 half4  __attribute__((ext_vector_type(4)));
typedef float    floatx4 __attribute__((ext_vector_type(4)));

#define AS1(p) ((__attribute__((address_space(1))) void*)(void*)(p))
#define AS3(p) ((__attribute__((address_space(3))) void*)(p))

// ---------------------------------------------------------------------------
// CSR build
// ---------------------------------------------------------------------------
__global__ void count_kernel(const int* __restrict__ src, const int* __restrict__ dst,
                             int* deg_mi, int* deg_di, int E) {
    int i = blockIdx.x * blockDim.x + threadIdx.x;
    if (i < E) {
        atomicAdd(&deg_mi[src[i]], 1);
        atomicAdd(&deg_di[dst[i]], 1);
    }
}

__global__ __launch_bounds__(1024) void scan_kernel(const int* __restrict__ deg_di,
                                                    const int* __restrict__ deg_mi,
                                                    int* row_di, int* row_mi) {
    const int* deg;
    int* row;
    int n;
    if (blockIdx.x == 0) { deg = deg_di; row = row_di; n = N_DI; }
    else                 { deg = deg_mi; row = row_mi; n = N_MI; }

    __shared__ int wsum[16];
    int t = threadIdx.x;
    int lane = t & 63;
    int w = t >> 6;
    int carry = 0;

    for (int base = 0; base < n; base += 1024) {
        int i = base + t;
        int v = (i < n) ? deg[i] : 0;
        int x = v;
        #pragma unroll
        for (int off = 1; off < 64; off <<= 1) {
            int y = __shfl_up(x, off, 64);
            if (lane >= off) x += y;
        }
        if (lane == 63) wsum[w] = x;
        __syncthreads();
        if (w == 0 && lane < 16) {
            int s = wsum[lane];
            #pragma unroll
            for (int off = 1; off < 16; off <<= 1) {
                int y = __shfl_up(s, off, 16);
                if (lane >= off) s += y;
            }
            wsum[lane] = s;
        }
        __syncthreads();
        int woff = (w == 0) ? 0 : wsum[w - 1];
        int incl = x + woff;
        if (i < n) row[i] = carry + incl - v;
        carry += wsum[15];
        __syncthreads();
    }
    if (t == 0) row[n] = carry;
}

__global__ void fill_kernel(const int* __restrict__ src, const int* __restrict__ dst,
                            const int* __restrict__ row_mi, const int* __restrict__ row_di,
                            int* cur_mi, int* cur_di, int* csr_mi, int* csr_di, int E) {
    int i = blockIdx.x * blockDim.x + threadIdx.x;
    if (i >= E) return;
    int s = src[i], d = dst[i];
    int p = atomicAdd(&cur_di[d], 1);
    csr_di[row_di[d] + p] = s;
    int q = atomicAdd(&cur_mi[s], 1);
    csr_mi[row_mi[s] + q] = d;
}

// ---------------------------------------------------------------------------
// fp32 -> fp16 x converts (row-major)
// ---------------------------------------------------------------------------
__global__ void cvt_kernel(const float* __restrict__ s, _Float16* __restrict__ d, int n4) {
    int i = blockIdx.x * blockDim.x + threadIdx.x;
    if (i < n4) {
        float4 v = ((const float4*)s)[i];
        half4 h = {(_Float16)v.x, (_Float16)v.y, (_Float16)v.z, (_Float16)v.w};
        ((half4*)d)[i] = h;
    }
}

// ---------------------------------------------------------------------------
// fp32 W -> fp16 FRAGMENT-LINEAR layout.
// Chunk c (16 B = 8 halves): lane=c&63, j=(c>>6)&3, k=(c>>8)%KI, p=(c>>8)/KI.
// Holds W[p*64 + j*16 + (lane&15)][k*32 + (lane>>4)*8 .. +8].
// GEMM then stages panels with contiguous global_load_lds and reads fragments
// with conflict-free lane-contiguous ds_read_b128.
// ---------------------------------------------------------------------------
struct CvtW {
    const float* s[14];
    _Float16* d[14];
    int K[14];
    int KI[14];
    int nch[14];
};

__global__ void cvtw_kernel(CvtW a) {
    int arr = blockIdx.y;
    int c = blockIdx.x * blockDim.x + threadIdx.x;
    if (c >= a.nch[arr]) return;
    int K = a.K[arr], KI = a.KI[arr];
    int lane = c & 63;
    int j = (c >> 6) & 3;
    int rest = c >> 8;
    int k = rest % KI;
    int p = rest / KI;
    int row = p * 64 + j * 16 + (lane & 15);
    int kcol = k * 32 + (lane >> 4) * 8;
    const float* s = a.s[arr] + (long)row * K + kcol;
    float4 u = *(const float4*)s;
    float4 v = *(const float4*)(s + 4);
    half8 h = {(_Float16)u.x, (_Float16)u.y, (_Float16)u.z, (_Float16)u.w,
               (_Float16)v.x, (_Float16)v.y, (_Float16)v.z, (_Float16)v.w};
    *(half8*)(a.d[arr] + (long)c * 8) = h;
}

// ---------------------------------------------------------------------------
// Mean aggregation: one node per wave (unchanged from R5)
// ---------------------------------------------------------------------------
template<int DIN>
__global__ __launch_bounds__(256) void agg2_kernel(const _Float16* __restrict__ hsrc,
                                                   const int* __restrict__ row,
                                                   const int* __restrict__ csr,
                                                   _Float16* __restrict__ out, int n) {
    constexpr int LPR = DIN / 8;
    constexpr int GR  = 64 / LPR;
    int node = blockIdx.x * 4 + (threadIdx.x >> 6);
    if (node >= n) return;
    int lane = threadIdx.x & 63;
    int g = lane / LPR, c = lane % LPR;
    int beg = row[node], end = row[node + 1];
    float acc[8] = {};
    #pragma unroll 2
    for (int j = beg + g; j < end; j += GR) {
        half8 v = *(const half8*)(hsrc + (long)csr[j] * DIN + c * 8);
        #pragma unroll
        for (int e = 0; e < 8; ++e) acc[e] += (float)v[e];
    }
    float inv = 1.f / (float)max(end - beg, 1);
    half8 o;
    #pragma unroll
    for (int e = 0; e < 8; ++e) {
        float s = acc[e];
        s += __shfl_down(s, 32);
        if (GR == 4) s += __shfl_down(s, 16);
        o[e] = (_Float16)(s * inv);
    }
    if (g == 0) *(half8*)(out + (long)node * DIN + c * 8) = o;
}

// ---------------------------------------------------------------------------
// LDS-weight fp16 MFMA GEMM.
// Block = 4 waves = 256 M-rows x 64 N-cols (wave: 64x64).
// W panel(s) staged once to LDS in fragment-linear order (contiguous both
// sides); k-loop: 4 global A loads + 4 conflict-free ds_reads + 16 MFMA.
// C = act(A1@W1^T [+ A2@W2^T] + bias [+ Cadd_f32]); grid=(Mpad/256, N/64).
// ---------------------------------------------------------------------------
template<int KI, bool DUAL>
__global__ __launch_bounds__(256, 3) void hgemm_l(
    const _Float16* __restrict__ A1, const _Float16* __restrict__ W1f,
    const _Float16* __restrict__ A2, const _Float16* __restrict__ W2f,
    const float* __restrict__ bias, const float* __restrict__ Cadd,
    _Float16* __restrict__ C, int M, int N, int relu)
{
    constexpr int K = KI * 32;
    constexpr int PANEL = KI * 2048;            // halves per matrix panel
    __shared__ _Float16 lds[(DUAL ? 2 : 1) * PANEL];

    const int tid = threadIdx.x;
    const int wave = tid >> 6, lane = tid & 63;
    const int quad = lane >> 4, lr = lane & 15;
    const int p = blockIdx.y;
    const long m0 = (long)blockIdx.x * 256 + wave * 64;

    // ---- stage W panel(s): contiguous global -> contiguous LDS ----
    {
        const _Float16* g1 = W1f + (long)p * PANEL;
        #pragma unroll
        for (int it = 0; it < KI; ++it) {
            int c = tid + it * 256;
            __builtin_amdgcn_global_load_lds(AS1(g1 + c * 8), AS3(&lds[c * 8]), 16, 0, 0);
        }
        if (DUAL) {
            const _Float16* g2 = W2f + (long)p * PANEL;
            #pragma unroll
            for (int it = 0; it < KI; ++it) {
                int c = tid + it * 256;
                __builtin_amdgcn_global_load_lds(AS1(g2 + c * 8), AS3(&lds[PANEL + c * 8]), 16, 0, 0);
            }
        }
    }
    __syncthreads();

    floatx4 acc[4][4] = {};

    #pragma unroll
    for (int pass = 0; pass < (DUAL ? 2 : 1); ++pass) {
        const _Float16* A = pass ? A2 : A1;
        const _Float16* base = lds + pass * PANEL;
        half8 af[2][4];
        #pragma unroll
        for (int i = 0; i < 4; ++i)
            af[0][i] = *(const half8*)(A + (m0 + i * 16 + lr) * K + quad * 8);
        #pragma unroll
        for (int k = 0; k < KI; ++k) {
            half8 bf[4];
            #pragma unroll
            for (int j = 0; j < 4; ++j)
                bf[j] = *(const half8*)&base[(k * 4 + j) * 512 + lane * 8];
            if (k + 1 < KI) {
                #pragma unroll
                for (int i = 0; i < 4; ++i)
                    af[(k + 1) & 1][i] = *(const half8*)(A + (m0 + i * 16 + lr) * K + (k + 1) * 32 + quad * 8);
            }
            #pragma unroll
            for (int i = 0; i < 4; ++i)
                #pragma unroll
                for (int j = 0; j < 4; ++j)
                    acc[i][j] = __builtin_amdgcn_mfma_f32_16x16x32_f16(af[k & 1][i], bf[j], acc[i][j], 0, 0, 0);
        }
    }

    // epilogue: C/D layout col(lane&15)=n, row(quad*4+r)=m
    const int n0 = p * 64;
    #pragma unroll
    for (int i = 0; i < 4; ++i) {
        int mb = (int)m0 + i * 16 + quad * 4;
        #pragma unroll
        for (int j = 0; j < 4; ++j) {
            int n = n0 + j * 16 + lr;
            float bn = bias[n];
            #pragma unroll
            for (int r = 0; r < 4; ++r) {
                int m = mb + r;
                if (m < M) {
                    float v = acc[i][j][r] + bn;
                    if (Cadd) v += Cadd[(long)m * N + n];
                    if (relu) v = fmaxf(v, 0.f);
                    C[(long)m * N + n] = (_Float16)v;
                }
            }
        }
    }
}

// ---------------------------------------------------------------------------
// Classifier: out[e] = dot64(h_mi[ls[e]], h_di[ld[e]]), fp16 in, fp32 out
// ---------------------------------------------------------------------------
__global__ void classify_kernel(const _Float16* __restrict__ hmi, const _Float16* __restrict__ hdi,
                                const int* __restrict__ ls, const int* __restrict__ ld,
                                float* __restrict__ out, int L) {
    long idx = (long)blockIdx.x * blockDim.x + threadIdx.x;
    int e = (int)(idx >> 4), q = (int)(idx & 15);
    if (e >= L) return;
    const half4* ra = (const half4*)(hmi + (long)ls[e] * 64);
    const half4* rb = (const half4*)(hdi + (long)ld[e] * 64);
    half4 a = ra[q], b = rb[q];
    float s = (float)a.x * (float)b.x + (float)a.y * (float)b.y +
              (float)a.z * (float)b.z + (float)a.w * (float)b.w;
    #pragma unroll
    for (int off = 8; off >= 1; off >>= 1) s += __shfl_down(s, off, 16);
    if (q == 0) out[e] = s;
}

// ---------------------------------------------------------------------------
// Launch
// ---------------------------------------------------------------------------
extern "C" void kernel_launch(void* const* d_in, const int* in_sizes, int n_in,
                              void* d_out, int out_size, void* d_ws, size_t ws_size,
                              hipStream_t stream) {
    const float* x_mi   = (const float*)d_in[0];
    const float* x_di   = (const float*)d_in[1];
    const float* W_mi   = (const float*)d_in[2];
    const float* b_mi   = (const float*)d_in[3];
    const float* W_di   = (const float*)d_in[4];
    const float* b_di   = (const float*)d_in[5];
    const float* emb_mi = (const float*)d_in[6];
    const float* emb_di = (const float*)d_in[7];
    const float* Wl1_md = (const float*)d_in[8];
    const float* bl1_md = (const float*)d_in[9];
    const float* Wr1_md = (const float*)d_in[10];
    const float* Wl1_dm = (const float*)d_in[11];
    const float* bl1_dm = (const float*)d_in[12];
    const float* Wr1_dm = (const float*)d_in[13];
    const float* Wl2_md = (const float*)d_in[14];
    const float* bl2_md = (const float*)d_in[15];
    const float* Wr2_md = (const float*)d_in[16];
    const float* Wl2_dm = (const float*)d_in[17];
    const float* bl2_dm = (const float*)d_in[18];
    const float* Wr2_dm = (const float*)d_in[19];
    const float* Wl3_md = (const float*)d_in[20];
    const float* bl3_md = (const float*)d_in[21];
    const float* Wr3_md = (const float*)d_in[22];
    const float* Wl3_dm = (const float*)d_in[23];
    const float* bl3_dm = (const float*)d_in[24];
    const float* Wr3_dm = (const float*)d_in[25];
    const int* edge_src  = (const int*)d_in[26];
    const int* edge_dst  = (const int*)d_in[27];
    const int* label_src = (const int*)d_in[28];
    const int* label_dst = (const int*)d_in[29];
    const int E = in_sizes[26];
    const int L = in_sizes[28];
    float* out = (float*)d_out;

    // ---- workspace layout (fp16 first, then ints) ----
    _Float16* hp = (_Float16*)d_ws;
    _Float16* xh_mi = hp; hp += (long)MI_P * 256;
    _Float16* xh_di = hp; hp += (long)DI_P * 128;
    _Float16* wWmi  = hp; hp += 128 * 256;
    _Float16* wWdi  = hp; hp += 128 * 128;
    _Float16* wl1md = hp; hp += 256 * 128;
    _Float16* wr1md = hp; hp += 256 * 128;
    _Float16* wl1dm = hp; hp += 256 * 128;
    _Float16* wr1dm = hp; hp += 256 * 128;
    _Float16* wl2md = hp; hp += 128 * 256;
    _Float16* wr2md = hp; hp += 128 * 256;
    _Float16* wl2dm = hp; hp += 128 * 256;
    _Float16* wr2dm = hp; hp += 128 * 256;
    _Float16* wl3md = hp; hp += 64 * 128;
    _Float16* wr3md = hp; hp += 64 * 128;
    _Float16* wl3dm = hp; hp += 64 * 128;
    _Float16* wr3dm = hp; hp += 64 * 128;
    _Float16* h_mi0 = hp; hp += (long)MI_P * 256;
    _Float16* h_mi1 = hp; hp += (long)MI_P * 256;
    _Float16* h_di0 = hp; hp += (long)DI_P * 256;
    _Float16* h_di1 = hp; hp += (long)DI_P * 256;
    _Float16* aggh  = hp; hp += (long)MI_P * 256;

    int* ip = (int*)hp;
    int* deg_di = ip;  ip += N_DI;
    int* deg_mi = ip;  ip += N_MI;
    int* cur_di = ip;  ip += N_DI;
    int* cur_mi = ip;  ip += N_MI;
    int* row_di = ip;  ip += N_DI + 1;
    int* row_mi = ip;  ip += N_MI + 1;
    int* csr_di = ip;  ip += E;
    int* csr_mi = ip;  ip += E;

    // ---- CSR build ----
    hipMemsetAsync(deg_di, 0, (size_t)(2 * (N_DI + N_MI)) * sizeof(int), stream);
    int eb = (E + 255) / 256;
    count_kernel<<<eb, 256, 0, stream>>>(edge_src, edge_dst, deg_mi, deg_di, E);
    scan_kernel<<<2, 1024, 0, stream>>>(deg_di, deg_mi, row_di, row_mi);
    fill_kernel<<<eb, 256, 0, stream>>>(edge_src, edge_dst, row_mi, row_di,
                                        cur_mi, cur_di, csr_mi, csr_di, E);

    // ---- x converts (row-major fp16) ----
    cvt_kernel<<<(N_MI * 256 / 4 + 255) / 256, 256, 0, stream>>>(x_mi, xh_mi, N_MI * 256 / 4);
    cvt_kernel<<<(N_DI * 128 / 4 + 255) / 256, 256, 0, stream>>>(x_di, xh_di, N_DI * 128 / 4);

    // ---- W converts -> fragment-linear fp16 ----
    CvtW cw;
    const float* srcs[14] = {W_mi, W_di, Wl1_md, Wr1_md, Wl1_dm, Wr1_dm,
                             Wl2_md, Wr2_md, Wl2_dm, Wr2_dm, Wl3_md, Wr3_md, Wl3_dm, Wr3_dm};
    _Float16* dsts[14] = {wWmi, wWdi, wl1md, wr1md, wl1dm, wr1dm,
                          wl2md, wr2md, wl2dm, wr2dm, wl3md, wr3md, wl3dm, wr3dm};
    int Ks[14]  = {256, 128, 128, 128, 128, 128, 256, 256, 256, 256, 128, 128, 128, 128};
    int Ns[14]  = {128, 128, 256, 256, 256, 256, 128, 128, 128, 128, 64, 64, 64, 64};
    for (int i = 0; i < 14; ++i) {
        cw.s[i] = srcs[i]; cw.d[i] = dsts[i];
        cw.K[i] = Ks[i]; cw.KI[i] = Ks[i] / 32;
        cw.nch[i] = Ns[i] * Ks[i] / 8;
    }
    cvtw_kernel<<<dim3(16, 14), 256, 0, stream>>>(cw);

    // ---- init: h0 = x @ W^T + b + emb ----
    hgemm_l<8, false><<<dim3(MI_P / 256, 2), 256, 0, stream>>>(
        xh_mi, wWmi, nullptr, nullptr, b_mi, emb_mi, h_mi0, N_MI, 128, 0);
    hgemm_l<4, false><<<dim3(DI_P / 256, 2), 256, 0, stream>>>(
        xh_di, wWdi, nullptr, nullptr, b_di, emb_di, h_di0, N_DI, 128, 0);

    // ---- Layer 1: 128 -> 256, relu ----
    agg2_kernel<128><<<(N_DI + 3) / 4, 256, 0, stream>>>(h_mi0, row_di, csr_di, aggh, N_DI);
    hgemm_l<4, true><<<dim3(DI_P / 256, 4), 256, 0, stream>>>(
        aggh, wl1md, h_di0, wr1md, bl1_md, nullptr, h_di1, N_DI, 256, 1);
    agg2_kernel<128><<<(N_MI + 3) / 4, 256, 0, stream>>>(h_di0, row_mi, csr_mi, aggh, N_MI);
    hgemm_l<4, true><<<dim3(MI_P / 256, 4), 256, 0, stream>>>(
        aggh, wl1dm, h_mi0, wr1dm, bl1_dm, nullptr, h_mi1, N_MI, 256, 1);

    // ---- Layer 2: 256 -> 128, relu ----
    agg2_kernel<256><<<(N_DI + 3) / 4, 256, 0, stream>>>(h_mi1, row_di, csr_di, aggh, N_DI);
    hgemm_l<8, true><<<dim3(DI_P / 256, 2), 256, 0, stream>>>(
        aggh, wl2md, h_di1, wr2md, bl2_md, nullptr, h_di0, N_DI, 128, 1);
    agg2_kernel<256><<<(N_MI + 3) / 4, 256, 0, stream>>>(h_di1, row_mi, csr_mi, aggh, N_MI);
    hgemm_l<8, true><<<dim3(MI_P / 256, 2), 256, 0, stream>>>(
        aggh, wl2dm, h_mi1, wr2dm, bl2_dm, nullptr, h_mi0, N_MI, 128, 1);

    // ---- Layer 3: 128 -> 64, no relu ----
    agg2_kernel<128><<<(N_DI + 3) / 4, 256, 0, stream>>>(h_mi0, row_di, csr_di, aggh, N_DI);
    hgemm_l<4, true><<<dim3(DI_P / 256, 1), 256, 0, stream>>>(
        aggh, wl3md, h_di0, wr3md, bl3_md, nullptr, h_di1, N_DI, 64, 0);
    agg2_kernel<128><<<(N_MI + 3) / 4, 256, 0, stream>>>(h_di0, row_mi, csr_mi, aggh, N_MI);
    hgemm_l<4, true><<<dim3(MI_P / 256, 1), 256, 0, stream>>>(
        aggh, wl3dm, h_mi0, wr3dm, bl3_dm, nullptr, h_mi1, N_MI, 64, 0);

    // ---- classifier ----
    classify_kernel<<<((long)L * 16 + 255) / 256, 256, 0, stream>>>(
        h_mi1, h_di1, label_src, label_dst, out, L);
}

// Round 7
// 965.961 us; speedup vs baseline: 1.2429x; 1.0067x over previous
//
#include <hip/hip_runtime.h>

#define N_MI 100000
#define N_DI 50000
#define MI_P 100352   // multiple of 256
#define DI_P 50176    // multiple of 256

typedef _Float16 half8  __attribute__((ext_vector_type(8)));
typedef _Float16 half4  __attribute__((ext_vector_type(4)));
typedef float    floatx4 __attribute__((ext_vector_type(4)));

// ---------------------------------------------------------------------------
// CSR build
// ---------------------------------------------------------------------------
__global__ void count_kernel(const int* __restrict__ src, const int* __restrict__ dst,
                             int* deg_mi, int* deg_di, int E) {
    int i = blockIdx.x * blockDim.x + threadIdx.x;
    if (i < E) {
        atomicAdd(&deg_mi[src[i]], 1);
        atomicAdd(&deg_di[dst[i]], 1);
    }
}

__global__ __launch_bounds__(1024) void scan_kernel(const int* __restrict__ deg_di,
                                                    const int* __restrict__ deg_mi,
                                                    int* row_di, int* row_mi) {
    const int* deg;
    int* row;
    int n;
    if (blockIdx.x == 0) { deg = deg_di; row = row_di; n = N_DI; }
    else                 { deg = deg_mi; row = row_mi; n = N_MI; }

    __shared__ int wsum[16];
    int t = threadIdx.x;
    int lane = t & 63;
    int w = t >> 6;
    int carry = 0;

    for (int base = 0; base < n; base += 1024) {
        int i = base + t;
        int v = (i < n) ? deg[i] : 0;
        int x = v;
        #pragma unroll
        for (int off = 1; off < 64; off <<= 1) {
            int y = __shfl_up(x, off, 64);
            if (lane >= off) x += y;
        }
        if (lane == 63) wsum[w] = x;
        __syncthreads();
        if (w == 0 && lane < 16) {
            int s = wsum[lane];
            #pragma unroll
            for (int off = 1; off < 16; off <<= 1) {
                int y = __shfl_up(s, off, 16);
                if (lane >= off) s += y;
            }
            wsum[lane] = s;
        }
        __syncthreads();
        int woff = (w == 0) ? 0 : wsum[w - 1];
        int incl = x + woff;
        if (i < n) row[i] = carry + incl - v;
        carry += wsum[15];
        __syncthreads();
    }
    if (t == 0) row[n] = carry;
}

__global__ void fill_kernel(const int* __restrict__ src, const int* __restrict__ dst,
                            const int* __restrict__ row_mi, const int* __restrict__ row_di,
                            int* cur_mi, int* cur_di, int* csr_mi, int* csr_di, int E) {
    int i = blockIdx.x * blockDim.x + threadIdx.x;
    if (i >= E) return;
    int s = src[i], d = dst[i];
    int p = atomicAdd(&cur_di[d], 1);
    csr_di[row_di[d] + p] = s;
    int q = atomicAdd(&cur_mi[s], 1);
    csr_mi[row_mi[s] + q] = d;
}

// ---------------------------------------------------------------------------
// Fragment-linear layout for an [Mpad x K] operand (K = KI*32):
//   chunk c (8 halves): lane=c&63 (lr=lane&15 -> row-in-16, q=lane>>4 -> ksub),
//   i=(c>>6)&3 (16-row group), k=(c>>8)%KI, mt=(c>>8)/KI (64-row tile).
//   element: row = mt*64+i*16+lr, col = k*32+q*8+e.
// A wave frag load (i,k) = 64 consecutive chunks = 1 KB contiguous.
// ---------------------------------------------------------------------------

// fp32 W [N x K] -> frag-linear fp16 (N-panels of 64)
struct CvtW {
    const float* s[14];
    _Float16* d[14];
    int K[14];
    int KI[14];
    int nch[14];
};

__global__ void cvtw_kernel(CvtW a) {
    int arr = blockIdx.y;
    int c = blockIdx.x * blockDim.x + threadIdx.x;
    if (c >= a.nch[arr]) return;
    int K = a.K[arr], KI = a.KI[arr];
    int lane = c & 63;
    int j = (c >> 6) & 3;
    int rest = c >> 8;
    int k = rest % KI;
    int p = rest / KI;
    int row = p * 64 + j * 16 + (lane & 15);
    int kcol = k * 32 + (lane >> 4) * 8;
    const float* s = a.s[arr] + (long)row * K + kcol;
    float4 u = *(const float4*)s;
    float4 v = *(const float4*)(s + 4);
    half8 h = {(_Float16)u.x, (_Float16)u.y, (_Float16)u.z, (_Float16)u.w,
               (_Float16)v.x, (_Float16)v.y, (_Float16)v.z, (_Float16)v.w};
    *(half8*)(a.d[arr] + (long)c * 8) = h;
}

// fp32 row-major [M x K] -> frag-linear fp16, LDS transpose, both sides stream.
template<int K>
__global__ __launch_bounds__(256) void cvt_frag(const float* __restrict__ in,
                                                _Float16* __restrict__ out, int M) {
    constexpr int KI = K / 32;
    constexpr int CPR = K / 8;              // chunks per row
    __shared__ _Float16 lds[64 * (K + 8)];
    const int tile = blockIdx.x;
    const int tid = threadIdx.x;
    // phase 1: contiguous read (+clamp), convert, padded LDS write
    #pragma unroll
    for (int it = 0; it < KI; ++it) {
        int c = tid + it * 256;             // 0 .. 8K-1
        int r = c / CPR, col = c % CPR;
        int row = tile * 64 + r;
        if (row >= M) row = M - 1;
        const float* g = in + (long)row * K + col * 8;
        float4 u = *(const float4*)g;
        float4 v = *(const float4*)(g + 4);
        half8 h = {(_Float16)u.x, (_Float16)u.y, (_Float16)u.z, (_Float16)u.w,
                   (_Float16)v.x, (_Float16)v.y, (_Float16)v.z, (_Float16)v.w};
        *(half8*)&lds[r * (K + 8) + col * 8] = h;
    }
    __syncthreads();
    // phase 2: frag-order LDS read (2-way free), contiguous global write
    #pragma unroll
    for (int it = 0; it < KI; ++it) {
        int c = tid + it * 256;
        int lane = c & 63, i = (c >> 6) & 3, k = c >> 8;
        half8 h = *(const half8*)&lds[(i * 16 + (lane & 15)) * (K + 8) + k * 32 + (lane >> 4) * 8];
        *(half8*)(out + ((long)tile * 8 * K + c) * 8) = h;
    }
}

// fp16 row-major [Mpad x K] -> frag-linear fp16 (same transpose, fp16 in)
template<int K>
__global__ __launch_bounds__(256) void repack(const _Float16* __restrict__ in,
                                              _Float16* __restrict__ out) {
    constexpr int KI = K / 32;
    constexpr int CPR = K / 8;
    __shared__ _Float16 lds[64 * (K + 8)];
    const int tile = blockIdx.x;
    const int tid = threadIdx.x;
    #pragma unroll
    for (int it = 0; it < KI; ++it) {
        int c = tid + it * 256;
        int r = c / CPR, col = c % CPR;
        half8 h = *(const half8*)(in + (long)tile * 64 * K + c * 8);
        *(half8*)&lds[r * (K + 8) + col * 8] = h;
    }
    __syncthreads();
    #pragma unroll
    for (int it = 0; it < KI; ++it) {
        int c = tid + it * 256;
        int lane = c & 63, i = (c >> 6) & 3, k = c >> 8;
        half8 h = *(const half8*)&lds[(i * 16 + (lane & 15)) * (K + 8) + k * 32 + (lane >> 4) * 8];
        *(half8*)(out + ((long)tile * 8 * K + c) * 8) = h;
    }
}

// ---------------------------------------------------------------------------
// Mean aggregation: one node per wave; reads row-major h, WRITES FRAG-LINEAR.
// ---------------------------------------------------------------------------
template<int DIN>
__global__ __launch_bounds__(256) void agg2_kernel(const _Float16* __restrict__ hsrc,
                                                   const int* __restrict__ row,
                                                   const int* __restrict__ csr,
                                                   _Float16* __restrict__ outf, int n) {
    constexpr int LPR = DIN / 8;
    constexpr int GR  = 64 / LPR;
    constexpr int KI  = DIN / 32;
    int node = blockIdx.x * 4 + (threadIdx.x >> 6);
    if (node >= n) return;
    int lane = threadIdx.x & 63;
    int g = lane / LPR, c = lane % LPR;
    int beg = row[node], end = row[node + 1];
    float acc[8] = {};
    #pragma unroll 2
    for (int j = beg + g; j < end; j += GR) {
        half8 v = *(const half8*)(hsrc + (long)csr[j] * DIN + c * 8);
        #pragma unroll
        for (int e = 0; e < 8; ++e) acc[e] += (float)v[e];
    }
    float inv = 1.f / (float)max(end - beg, 1);
    half8 o;
    #pragma unroll
    for (int e = 0; e < 8; ++e) {
        float s = acc[e];
        s += __shfl_down(s, 32);
        if (GR == 4) s += __shfl_down(s, 16);
        o[e] = (_Float16)(s * inv);
    }
    if (g == 0) {
        int mt = node >> 6, ii = (node >> 4) & 3, lrm = node & 15;
        long off = (((long)mt * KI + (c >> 2)) * 4 + ii) * 512 + (lrm + 16 * (c & 3)) * 8;
        *(half8*)(outf + off) = o;
    }
}

// ---------------------------------------------------------------------------
// Fragment-linear fp16 MFMA GEMM: all loads are contiguous 1-KB wave streams.
// Block = 4 waves, each one 64x64 tile stacked along M. No LDS, no barriers.
// C = act(A1@W1^T [+ A2@W2^T] + bias [+ Cadd_f32]); grid (Mpad/256, N/64).
// ---------------------------------------------------------------------------
template<int KI, bool DUAL>
__global__ __launch_bounds__(256, 3) void hgemm_f(
    const _Float16* __restrict__ A1f, const _Float16* __restrict__ W1f,
    const _Float16* __restrict__ A2f, const _Float16* __restrict__ W2f,
    const float* __restrict__ bias, const float* __restrict__ Cadd,
    _Float16* __restrict__ C, int M, int N, int relu)
{
    const int wave = threadIdx.x >> 6, lane = threadIdx.x & 63;
    const int quad = lane >> 4, lr = lane & 15;
    const int mt = blockIdx.x * 4 + wave;   // 64-row tile
    const int p = blockIdx.y;               // 64-col panel
    const long abase = ((long)mt * KI * 4) * 512 + lane * 8;
    const long wbase = ((long)p  * KI * 4) * 512 + lane * 8;

    floatx4 acc[4][4] = {};

    #pragma unroll
    for (int pass = 0; pass < (DUAL ? 2 : 1); ++pass) {
        const _Float16* A = pass ? A2f : A1f;
        const _Float16* W = pass ? W2f : W1f;
        #pragma unroll
        for (int k = 0; k < KI; ++k) {
            half8 af[4], bf[4];
            #pragma unroll
            for (int i = 0; i < 4; ++i)
                af[i] = *(const half8*)(A + abase + (k * 4 + i) * 512);
            #pragma unroll
            for (int j = 0; j < 4; ++j)
                bf[j] = *(const half8*)(W + wbase + (k * 4 + j) * 512);
            #pragma unroll
            for (int i = 0; i < 4; ++i)
                #pragma unroll
                for (int j = 0; j < 4; ++j)
                    acc[i][j] = __builtin_amdgcn_mfma_f32_16x16x32_f16(af[i], bf[j], acc[i][j], 0, 0, 0);
        }
    }

    // epilogue: C/D layout col(lane&15)=n, row(quad*4+r)=m
    const int m0 = mt * 64, n0 = p * 64;
    #pragma unroll
    for (int i = 0; i < 4; ++i) {
        int mb = m0 + i * 16 + quad * 4;
        #pragma unroll
        for (int j = 0; j < 4; ++j) {
            int n = n0 + j * 16 + lr;
            float bn = bias[n];
            #pragma unroll
            for (int r = 0; r < 4; ++r) {
                int m = mb + r;
                if (m < M) {
                    float v = acc[i][j][r] + bn;
                    if (Cadd) v += Cadd[(long)m * N + n];
                    if (relu) v = fmaxf(v, 0.f);
                    C[(long)m * N + n] = (_Float16)v;
                }
            }
        }
    }
}

// ---------------------------------------------------------------------------
// Classifier: out[e] = dot64(h_mi[ls[e]], h_di[ld[e]]), fp16 in, fp32 out
// ---------------------------------------------------------------------------
__global__ void classify_kernel(const _Float16* __restrict__ hmi, const _Float16* __restrict__ hdi,
                                const int* __restrict__ ls, const int* __restrict__ ld,
                                float* __restrict__ out, int L) {
    long idx = (long)blockIdx.x * blockDim.x + threadIdx.x;
    int e = (int)(idx >> 4), q = (int)(idx & 15);
    if (e >= L) return;
    const half4* ra = (const half4*)(hmi + (long)ls[e] * 64);
    const half4* rb = (const half4*)(hdi + (long)ld[e] * 64);
    half4 a = ra[q], b = rb[q];
    float s = (float)a.x * (float)b.x + (float)a.y * (float)b.y +
              (float)a.z * (float)b.z + (float)a.w * (float)b.w;
    #pragma unroll
    for (int off = 8; off >= 1; off >>= 1) s += __shfl_down(s, off, 16);
    if (q == 0) out[e] = s;
}

// ---------------------------------------------------------------------------
// Launch
// ---------------------------------------------------------------------------
extern "C" void kernel_launch(void* const* d_in, const int* in_sizes, int n_in,
                              void* d_out, int out_size, void* d_ws, size_t ws_size,
                              hipStream_t stream) {
    const float* x_mi   = (const float*)d_in[0];
    const float* x_di   = (const float*)d_in[1];
    const float* W_mi   = (const float*)d_in[2];
    const float* b_mi   = (const float*)d_in[3];
    const float* W_di   = (const float*)d_in[4];
    const float* b_di   = (const float*)d_in[5];
    const float* emb_mi = (const float*)d_in[6];
    const float* emb_di = (const float*)d_in[7];
    const float* Wl1_md = (const float*)d_in[8];
    const float* bl1_md = (const float*)d_in[9];
    const float* Wr1_md = (const float*)d_in[10];
    const float* Wl1_dm = (const float*)d_in[11];
    const float* bl1_dm = (const float*)d_in[12];
    const float* Wr1_dm = (const float*)d_in[13];
    const float* Wl2_md = (const float*)d_in[14];
    const float* bl2_md = (const float*)d_in[15];
    const float* Wr2_md = (const float*)d_in[16];
    const float* Wl2_dm = (const float*)d_in[17];
    const float* bl2_dm = (const float*)d_in[18];
    const float* Wr2_dm = (const float*)d_in[19];
    const float* Wl3_md = (const float*)d_in[20];
    const float* bl3_md = (const float*)d_in[21];
    const float* Wr3_md = (const float*)d_in[22];
    const float* Wl3_dm = (const float*)d_in[23];
    const float* bl3_dm = (const float*)d_in[24];
    const float* Wr3_dm = (const float*)d_in[25];
    const int* edge_src  = (const int*)d_in[26];
    const int* edge_dst  = (const int*)d_in[27];
    const int* label_src = (const int*)d_in[28];
    const int* label_dst = (const int*)d_in[29];
    const int E = in_sizes[26];
    const int L = in_sizes[28];
    float* out = (float*)d_out;

    // ---- workspace layout ----
    _Float16* hp = (_Float16*)d_ws;
    _Float16* wWmi  = hp; hp += 128 * 256;
    _Float16* wWdi  = hp; hp += 128 * 128;
    _Float16* wl1md = hp; hp += 256 * 128;
    _Float16* wr1md = hp; hp += 256 * 128;
    _Float16* wl1dm = hp; hp += 256 * 128;
    _Float16* wr1dm = hp; hp += 256 * 128;
    _Float16* wl2md = hp; hp += 128 * 256;
    _Float16* wr2md = hp; hp += 128 * 256;
    _Float16* wl2dm = hp; hp += 128 * 256;
    _Float16* wr2dm = hp; hp += 128 * 256;
    _Float16* wl3md = hp; hp += 64 * 128;
    _Float16* wr3md = hp; hp += 64 * 128;
    _Float16* wl3dm = hp; hp += 64 * 128;
    _Float16* wr3dm = hp; hp += 64 * 128;
    _Float16* h_mi0 = hp; hp += (long)MI_P * 256;   // row-major h (mi)
    _Float16* h_mi1 = hp; hp += (long)MI_P * 256;
    _Float16* h_di0 = hp; hp += (long)DI_P * 256;
    _Float16* h_di1 = hp; hp += (long)DI_P * 256;
    _Float16* hf_mi = hp; hp += (long)MI_P * 256;   // frag-linear root copy / init x
    _Float16* hf_di = hp; hp += (long)DI_P * 256;
    _Float16* agghf = hp; hp += (long)MI_P * 256;   // frag-linear agg output

    int* ip = (int*)hp;
    int* deg_di = ip;  ip += N_DI;
    int* deg_mi = ip;  ip += N_MI;
    int* cur_di = ip;  ip += N_DI;
    int* cur_mi = ip;  ip += N_MI;
    int* row_di = ip;  ip += N_DI + 1;
    int* row_mi = ip;  ip += N_MI + 1;
    int* csr_di = ip;  ip += E;
    int* csr_mi = ip;  ip += E;

    // ---- CSR build ----
    hipMemsetAsync(deg_di, 0, (size_t)(2 * (N_DI + N_MI)) * sizeof(int), stream);
    int eb = (E + 255) / 256;
    count_kernel<<<eb, 256, 0, stream>>>(edge_src, edge_dst, deg_mi, deg_di, E);
    scan_kernel<<<2, 1024, 0, stream>>>(deg_di, deg_mi, row_di, row_mi);
    fill_kernel<<<eb, 256, 0, stream>>>(edge_src, edge_dst, row_mi, row_di,
                                        cur_mi, cur_di, csr_mi, csr_di, E);

    // ---- W converts -> frag-linear fp16 ----
    CvtW cw;
    const float* srcs[14] = {W_mi, W_di, Wl1_md, Wr1_md, Wl1_dm, Wr1_dm,
                             Wl2_md, Wr2_md, Wl2_dm, Wr2_dm, Wl3_md, Wr3_md, Wl3_dm, Wr3_dm};
    _Float16* dsts[14] = {wWmi, wWdi, wl1md, wr1md, wl1dm, wr1dm,
                          wl2md, wr2md, wl2dm, wr2dm, wl3md, wr3md, wl3dm, wr3dm};
    int Ks[14]  = {256, 128, 128, 128, 128, 128, 256, 256, 256, 256, 128, 128, 128, 128};
    int Ns[14]  = {128, 128, 256, 256, 256, 256, 128, 128, 128, 128, 64, 64, 64, 64};
    for (int i = 0; i < 14; ++i) {
        cw.s[i] = srcs[i]; cw.d[i] = dsts[i];
        cw.K[i] = Ks[i]; cw.KI[i] = Ks[i] / 32;
        cw.nch[i] = Ns[i] * Ks[i] / 8;
    }
    cvtw_kernel<<<dim3(16, 14), 256, 0, stream>>>(cw);

    // ---- x -> frag-linear fp16 (aliased into hf buffers) ----
    cvt_frag<256><<<MI_P / 64, 256, 0, stream>>>(x_mi, hf_mi, N_MI);
    cvt_frag<128><<<DI_P / 64, 256, 0, stream>>>(x_di, hf_di, N_DI);

    // ---- init: h0 = x @ W^T + b + emb ----
    hgemm_f<8, false><<<dim3(MI_P / 256, 2), 256, 0, stream>>>(
        hf_mi, wWmi, nullptr, nullptr, b_mi, emb_mi, h_mi0, N_MI, 128, 0);
    hgemm_f<4, false><<<dim3(DI_P / 256, 2), 256, 0, stream>>>(
        hf_di, wWdi, nullptr, nullptr, b_di, emb_di, h_di0, N_DI, 128, 0);

    // ---- Layer 1: 128 -> 256, relu ----
    repack<128><<<MI_P / 64, 256, 0, stream>>>(h_mi0, hf_mi);
    repack<128><<<DI_P / 64, 256, 0, stream>>>(h_di0, hf_di);
    agg2_kernel<128><<<(N_DI + 3) / 4, 256, 0, stream>>>(h_mi0, row_di, csr_di, agghf, N_DI);
    hgemm_f<4, true><<<dim3(DI_P / 256, 4), 256, 0, stream>>>(
        agghf, wl1md, hf_di, wr1md, bl1_md, nullptr, h_di1, N_DI, 256, 1);
    agg2_kernel<128><<<(N_MI + 3) / 4, 256, 0, stream>>>(h_di0, row_mi, csr_mi, agghf, N_MI);
    hgemm_f<4, true><<<dim3(MI_P / 256, 4), 256, 0, stream>>>(
        agghf, wl1dm, hf_mi, wr1dm, bl1_dm, nullptr, h_mi1, N_MI, 256, 1);

    // ---- Layer 2: 256 -> 128, relu ----
    repack<256><<<MI_P / 64, 256, 0, stream>>>(h_mi1, hf_mi);
    repack<256><<<DI_P / 64, 256, 0, stream>>>(h_di1, hf_di);
    agg2_kernel<256><<<(N_DI + 3) / 4, 256, 0, stream>>>(h_mi1, row_di, csr_di, agghf, N_DI);
    hgemm_f<8, true><<<dim3(DI_P / 256, 2), 256, 0, stream>>>(
        agghf, wl2md, hf_di, wr2md, bl2_md, nullptr, h_di0, N_DI, 128, 1);
    agg2_kernel<256><<<(N_MI + 3) / 4, 256, 0, stream>>>(h_di1, row_mi, csr_mi, agghf, N_MI);
    hgemm_f<8, true><<<dim3(MI_P / 256, 2), 256, 0, stream>>>(
        agghf, wl2dm, hf_mi, wr2dm, bl2_dm, nullptr, h_mi0, N_MI, 128, 1);

    // ---- Layer 3: 128 -> 64, no relu ----
    repack<128><<<MI_P / 64, 256, 0, stream>>>(h_mi0, hf_mi);
    repack<128><<<DI_P / 64, 256, 0, stream>>>(h_di0, hf_di);
    agg2_kernel<128><<<(N_DI + 3) / 4, 256, 0, stream>>>(h_mi0, row_di, csr_di, agghf, N_DI);
    hgemm_f<4, true><<<dim3(DI_P / 256, 1), 256, 0, stream>>>(
        agghf, wl3md, hf_di, wr3md, bl3_md, nullptr, h_di1, N_DI, 64, 0);
    agg2_kernel<128><<<(N_MI + 3) / 4, 256, 0, stream>>>(h_di0, row_mi, csr_mi, agghf, N_MI);
    hgemm_f<4, true><<<dim3(MI_P / 256, 1), 256, 0, stream>>>(
        agghf, wl3dm, hf_mi, wr3dm, bl3_dm, nullptr, h_mi1, N_MI, 64, 0);

    // ---- classifier ----
    classify_kernel<<<((long)L * 16 + 255) / 256, 256, 0, stream>>>(
        h_mi1, h_di1, label_src, label_dst, out, L);
}